// Round 1
// baseline (411.069 us; speedup 1.0000x reference)
//
#include <hip/hip_runtime.h>

typedef __attribute__((ext_vector_type(4))) float float4v;

// Barrier-free, LDS-free formulation.
// 4096 blocks x 256 threads; each 128-thread half handles one 2x2 window.
// Thread = (variant v, query token tok, head h). All K/V re-reads are L1 hits
// (16 KB window working set vs 32 KB L1); token-lanes read identical K/V
// addresses -> coalescer broadcast. All global loads use base + 13-bit imm
// offsets (tk stride 1024 B, j stride 16 B fit; row+1 gets its own base).
__global__ __launch_bounds__(256, 4) void cattn_kernel(
    const float* __restrict__ rr, const float* __restrict__ gg,
    const float* __restrict__ bb, const float* __restrict__ ii,
    const float* __restrict__ w0, const float* __restrict__ b0,
    const float* __restrict__ w1, const float* __restrict__ b1,
    const float* __restrict__ w2, const float* __restrict__ b2,
    const float* __restrict__ w3, const float* __restrict__ b3,
    float* __restrict__ out)
{
    const int t   = threadIdx.x;
    const int th  = t & 127;
    const int wid = (blockIdx.x << 1) | (t >> 7);   // window id 0..8191

    const int v   = th >> 5;          // variant 0..3
    const int tok = (th >> 3) & 3;    // query token 0..3
    const int h   = th & 7;           // head 0..7
    const int kvt = (v == 3) ? 1 : (v + 1);   // kv tensor: g,b,ir,g

    const int bi  = wid >> 10;
    const int rem = wid & 1023;
    const int y0  = (rem >> 5) << 1;
    const int x0  = (rem & 31) << 1;
    const int dy  = tok >> 1, dx = tok & 1;

    const float* srcs[4] = { rr, gg, bb, ii };
    const size_t base00 = ((size_t)(bi * 64 + y0) * 64 + (size_t)x0) * 256;

    const float* qp = srcs[v]   + base00 + (size_t)(dy * 16384 + dx * 256 + h * 32);
    const float* k0 = srcs[kvt] + base00 + (size_t)(h * 32);  // row y0: tk0 @+0, tk1 @+256
    const float* k1 = k0 + 16384;                             // row y0+1: tk2 @+0, tk3 @+256

    // q fragment (doubles as the residual)
    float q[32];
    #pragma unroll
    for (int j = 0; j < 8; ++j) {
        float4v c = *(const float4v*)(qp + j * 4);
        #pragma unroll
        for (int e = 0; e < 4; ++e) q[j * 4 + e] = c[e];
    }

    // pass 1: scores (4 keys)
    float s0 = 0.f, s1 = 0.f, s2 = 0.f, s3 = 0.f;
    #pragma unroll
    for (int j = 0; j < 8; ++j) {
        float4v c0 = *(const float4v*)(k0 + j * 4);
        float4v c1 = *(const float4v*)(k0 + 256 + j * 4);
        float4v c2 = *(const float4v*)(k1 + j * 4);
        float4v c3 = *(const float4v*)(k1 + 256 + j * 4);
        #pragma unroll
        for (int e = 0; e < 4; ++e) {
            const float qe = q[j * 4 + e];
            s0 += qe * c0[e];
            s1 += qe * c1[e];
            s2 += qe * c2[e];
            s3 += qe * c3[e];
        }
    }
    const float scale = 0.17677669529663687f;   // 1/sqrt(32)
    s0 *= scale; s1 *= scale; s2 *= scale; s3 *= scale;

    // softmax over 4
    const float mx = fmaxf(fmaxf(s0, s1), fmaxf(s2, s3));
    float p0 = __expf(s0 - mx), p1 = __expf(s1 - mx),
          p2 = __expf(s2 - mx), p3 = __expf(s3 - mx);
    const float inv = 1.f / (p0 + p1 + p2 + p3);
    p0 *= inv; p1 *= inv; p2 *= inv; p3 *= inv;

    // pass 2: o = residual + P.V  (V reloads are L1 hits)
    float o[32];
    #pragma unroll
    for (int j = 0; j < 8; ++j) {
        float4v c0 = *(const float4v*)(k0 + j * 4);
        float4v c1 = *(const float4v*)(k0 + 256 + j * 4);
        float4v c2 = *(const float4v*)(k1 + j * 4);
        float4v c3 = *(const float4v*)(k1 + 256 + j * 4);
        #pragma unroll
        for (int e = 0; e < 4; ++e) {
            o[j * 4 + e] = q[j * 4 + e]
                         + p0 * c0[e] + p1 * c1[e] + p2 * c2[e] + p3 * c3[e];
        }
    }

    // LayerNorm over 256 channels: reduce across the 8 head-lanes
    float sum = 0.f, sq = 0.f;
    #pragma unroll
    for (int c = 0; c < 32; ++c) { sum += o[c]; sq += o[c] * o[c]; }
    #pragma unroll
    for (int off = 1; off < 8; off <<= 1) {
        sum += __shfl_xor(sum, off, 64);
        sq  += __shfl_xor(sq,  off, 64);
    }
    const float mu  = sum * (1.f / 256.f);
    const float var = sq * (1.f / 256.f) - mu * mu;
    const float rs  = rsqrtf(var + 1e-5f);

    // LN params re-loaded per window (2 KB/tensor, permanently L1/L2-hot)
    const float* lw = ((v & 2) ? ((v & 1) ? w3 : w2) : ((v & 1) ? w1 : w0)) + h * 32;
    const float* lb = ((v & 2) ? ((v & 1) ? b3 : b2) : ((v & 1) ? b1 : b0)) + h * 32;

    float* op = out + ((size_t)(bi * 64 + y0 + dy) * 64 + (size_t)(x0 + dx)) * 1024
                    + (size_t)(v * 256 + h * 32);
    #pragma unroll
    for (int j = 0; j < 8; ++j) {
        float4v wv = *(const float4v*)(lw + j * 4);
        float4v bv = *(const float4v*)(lb + j * 4);
        float4v ov;
        #pragma unroll
        for (int e = 0; e < 4; ++e)
            ov[e] = (o[j * 4 + e] - mu) * rs * wv[e] + bv[e];
        *(float4v*)(op + j * 4) = ov;
    }
}

extern "C" void kernel_launch(void* const* d_in, const int* in_sizes, int n_in,
                              void* d_out, int out_size, void* d_ws, size_t ws_size,
                              hipStream_t stream) {
    (void)in_sizes; (void)n_in; (void)d_ws; (void)ws_size; (void)out_size;
    const float* rr = (const float*)d_in[0];
    const float* gg = (const float*)d_in[1];
    const float* bb = (const float*)d_in[2];
    const float* ii = (const float*)d_in[3];
    const float* w0 = (const float*)d_in[4];
    const float* b0 = (const float*)d_in[5];
    const float* w1 = (const float*)d_in[6];
    const float* b1 = (const float*)d_in[7];
    const float* w2 = (const float*)d_in[8];
    const float* b2 = (const float*)d_in[9];
    const float* w3 = (const float*)d_in[10];
    const float* b3 = (const float*)d_in[11];
    float* out = (float*)d_out;

    cattn_kernel<<<4096, 256, 0, stream>>>(rr, gg, bb, ii,
                                           w0, b0, w1, b1, w2, b2, w3, b3, out);
}